// Round 1
// baseline (22981.744 us; speedup 1.0000x reference)
//
#include <hip/hip_runtime.h>
#include <hip/hip_bf16.h>

// ---------- types ----------
typedef __bf16 v8bf __attribute__((ext_vector_type(8)));
typedef float  v4f  __attribute__((ext_vector_type(4)));

__device__ inline const __attribute__((address_space(1))) void* gcast(const void* p) {
    return (const __attribute__((address_space(1))) void*)p;
}
__device__ inline __attribute__((address_space(3))) void* scast(void* p) {
    return (__attribute__((address_space(3))) void*)p;
}

__device__ inline float fast_tanh(float x) {
    // tanh(x) = 1 - 2/(exp(2x)+1); __expf handles +/-inf limits correctly
    float e = __expf(2.0f * x);
    return 1.0f - 2.0f / (e + 1.0f);
}

// ---------- setup kernel 1: SE = z @ dec_W + dec_b  (128 x 2048) ----------
__global__ __launch_bounds__(256) void se_kernel(const float* __restrict__ z,
                                                 const float* __restrict__ decW,
                                                 const float* __restrict__ decb,
                                                 float* __restrict__ SE) {
    __shared__ float zs[128];
    const int b = blockIdx.x, t = threadIdx.x;
    if (t < 128) zs[t] = z[b * 128 + t];
    __syncthreads();
    for (int c = t; c < 2048; c += 256) {
        float acc = decb[c];
        #pragma unroll 4
        for (int k = 0; k < 128; ++k) acc += zs[k] * decW[k * 2048 + c];
        SE[b * 2048 + c] = acc;
    }
}

// ---------- setup kernel 2: deformation + aliveness + y0 assembly ----------
__global__ __launch_bounds__(128) void init_kernel(
    const float* __restrict__ SE, const float* __restrict__ tmpl,
    const float* __restrict__ dW1, const float* __restrict__ db1,
    const float* __restrict__ dW2, const float* __restrict__ db2,
    const float* __restrict__ aW1, const float* __restrict__ ab1,
    const float* __restrict__ aW2, const float* __restrict__ ab2,
    float* __restrict__ y, __bf16* __restrict__ ybf, float* __restrict__ out0) {
    __shared__ float se[64];
    __shared__ float h[128];
    __shared__ float ah[32];
    __shared__ float alive;
    const int r = blockIdx.x, b = r >> 5, s = r & 31, t = threadIdx.x;
    if (t < 64) se[t] = SE[b * 2048 + s * 64 + t];
    __syncthreads();
    {
        float acc = db1[t];
        #pragma unroll 4
        for (int k = 0; k < 64; ++k) acc += se[k] * dW1[k * 128 + t];
        h[t] = fmaxf(acc, 0.0f);
    }
    if (t < 32) {
        float acc = ab1[t];
        #pragma unroll 4
        for (int k = 0; k < 64; ++k) acc += se[k] * aW1[k * 32 + t];
        ah[t] = fmaxf(acc, 0.0f);
    }
    __syncthreads();
    if (t == 0) {
        float lg = ab2[0];
        #pragma unroll
        for (int j = 0; j < 32; ++j) lg += ah[j] * aW2[j];
        alive = 1.0f / (1.0f + __expf(-lg));
    }
    __syncthreads();
    if (t < 99) {
        float acc = db2[t];
        #pragma unroll 4
        for (int j = 0; j < 128; ++j) acc += h[j] * dW2[j * 99 + t];
        float v = (tmpl[s * 99 + t] + acc) * alive;
        int idx = b * 3200 + s * 99 + t;
        y[idx] = v; ybf[idx] = (__bf16)v; out0[idx] = v;
    } else if (t == 99) {
        int idx = b * 3200 + 3168 + s;
        y[idx] = alive; ybf[idx] = (__bf16)alive; out0[idx] = alive;
    }
}

// ---------- transpose fp32 (R x C) -> bf16 (C x R) ----------
__global__ __launch_bounds__(256) void transpose_bf16(const float* __restrict__ W,
                                                      __bf16* __restrict__ WT,
                                                      int R, int C) {
    __shared__ float tile[32][33];
    const int tx = threadIdx.x & 31, ty = threadIdx.x >> 5;
    const int c0 = blockIdx.x * 32, r0 = blockIdx.y * 32;
    #pragma unroll
    for (int i = 0; i < 4; ++i)
        tile[ty + 8 * i][tx] = W[(long)(r0 + ty + 8 * i) * C + c0 + tx];
    __syncthreads();
    #pragma unroll
    for (int i = 0; i < 4; ++i)
        WT[(long)(c0 + ty + 8 * i) * R + r0 + tx] = (__bf16)tile[tx][ty + 8 * i];
}

// ---------- main GEMM: C(128 x N) = A(128 x K, bf16) * BT(N x K, bf16)^T ----------
// BM=32, BN=32, BK=128, 256 threads (4 waves: wn = w&1 col-half, wk = w>>1 K-half).
// 4-deep LDS pipeline (64 KB), counted vmcnt (8/4/0 — never drains in steady state),
// one raw s_barrier per K-iter. Cross-wk reduction via LDS at the end; epilogue by
// waves 0-1 (identical fragment/epilogue layout to the verified BN=64 kernel).
// Grid is XCD-grouped: the 4 mt-blocks sharing one B-strip get bids = same (mod 8)
// so they land on one XCD's L2. nTiles counts 32-wide N tiles; launch
// grid = ceil(nTiles/8)*32; blocks with nt >= nTiles early-exit.
// mode 0: H = tanh(C + bias) -> obf (bf16)                       [phase 1]
// mode 1: k=C+bias; S=k;      ybf=bf16(y + cc*k)                 [eval 1]
// mode 2: k=C+bias; S+=2k;    ybf=bf16(y + cc*k)                 [evals 2,3]
// mode 3: k=C+bias; yn=y+dt6*(S+k); y=yn; ybf=bf16(yn); traj=yn  [eval 4]
__global__ __launch_bounds__(256, 2) void gemm_step(
    const __bf16* __restrict__ A, const __bf16* __restrict__ BT,
    const float* __restrict__ bias, int K, int nTiles, int mode, float cc, float dt6,
    __bf16* __restrict__ obf, float* __restrict__ y, float* __restrict__ S,
    float* __restrict__ traj) {
    // lds[buf][0] = A tile 32x128, lds[buf][1] = B tile 32x128 (each 8 KB)
    // XOR-swizzled chunk layout: chunk(row, c) stored at slot row*16 + (c ^ (row&15));
    // staging is contiguous 16B/lane (global_load_lds-compatible), reads are
    // minimum-aliasing (8 lanes per bank-quad across the wave) -> conflict-free.
    __shared__ __attribute__((aligned(16))) __bf16 lds[4][2][4096];

    const int t = threadIdx.x;
    const int lane = t & 63, w = t >> 6, q = lane >> 4, c16 = lane & 15;

    const int g = blockIdx.x >> 5, rr = blockIdx.x & 31;
    const int nt = g * 8 + (rr & 7);
    const int mt = rr >> 3;
    if (nt >= nTiles) return;
    const int m0 = mt * 32, n0 = nt * 32;
    const int N = nTiles * 32;

    // staging: thread t stages 4 chunks/iter (2 A rows, 2 B rows, same chunk slot)
    const int sr = t >> 4;               // 0..15
    const int scg = (t & 15) ^ sr;       // global chunk for stored slot (t&15)
    const __bf16* pA0 = A  + (long)(m0 + sr)      * K + scg * 8;
    const __bf16* pA1 = A  + (long)(m0 + sr + 16) * K + scg * 8;  // (sr+16)&15 == sr
    const __bf16* pB0 = BT + (long)(n0 + sr)      * K + scg * 8;
    const __bf16* pB1 = BT + (long)(n0 + sr + 16) * K + scg * 8;

    v4f acc0 = {0.f, 0.f, 0.f, 0.f};
    v4f acc1 = {0.f, 0.f, 0.f, 0.f};

    const int wn = w & 1, wk = w >> 1;
    const int rowA0 = c16, rowA1 = c16 + 16, rowB = wn * 16 + c16;
    const int swz = c16;                 // rowA0&15 == rowA1&15 == rowB&15 == c16
    const int cb = wk * 8;               // this wave's K-half: chunks cb..cb+7

    const int nIter = K >> 7;

#define STAGE(buf, koff) do { \
    __builtin_amdgcn_global_load_lds(gcast(pA0 + (koff)), scast(&lds[buf][0][t * 8]),         16, 0, 0); \
    __builtin_amdgcn_global_load_lds(gcast(pA1 + (koff)), scast(&lds[buf][0][(t + 256) * 8]), 16, 0, 0); \
    __builtin_amdgcn_global_load_lds(gcast(pB0 + (koff)), scast(&lds[buf][1][t * 8]),         16, 0, 0); \
    __builtin_amdgcn_global_load_lds(gcast(pB1 + (koff)), scast(&lds[buf][1][(t + 256) * 8]), 16, 0, 0); \
} while (0)

    // prologue: prefetch 3 tiles ahead
    STAGE(0, 0);
    if (nIter > 1) STAGE(1, 128);
    if (nIter > 2) STAGE(2, 256);

    for (int it = 0; it < nIter; ++it) {
        const int ahead = nIter - 1 - it;
        __builtin_amdgcn_sched_barrier(0);
        if (ahead >= 2)      asm volatile("s_waitcnt vmcnt(8)" ::: "memory");
        else if (ahead == 1) asm volatile("s_waitcnt vmcnt(4)" ::: "memory");
        else                 asm volatile("s_waitcnt vmcnt(0)" ::: "memory");
        __builtin_amdgcn_sched_barrier(0);
        __builtin_amdgcn_s_barrier();       // cur filled; everyone done with it-1
        __builtin_amdgcn_sched_barrier(0);
        // refill the buffer freed at iter it-1 ((it+3)&3 == (it-1)&3)
        if (it + 3 < nIter) STAGE((it + 3) & 3, (it + 3) * 128);

        const __bf16* bufA = lds[it & 3][0];
        const __bf16* bufB = lds[it & 3][1];
        v8bf a00 = *(const v8bf*)&bufA[(rowA0 * 16 + ((cb + q)     ^ swz)) * 8];
        v8bf a10 = *(const v8bf*)&bufA[(rowA1 * 16 + ((cb + q)     ^ swz)) * 8];
        v8bf b0  = *(const v8bf*)&bufB[(rowB  * 16 + ((cb + q)     ^ swz)) * 8];
        v8bf a01 = *(const v8bf*)&bufA[(rowA0 * 16 + ((cb + 4 + q) ^ swz)) * 8];
        v8bf a11 = *(const v8bf*)&bufA[(rowA1 * 16 + ((cb + 4 + q) ^ swz)) * 8];
        v8bf b1  = *(const v8bf*)&bufB[(rowB  * 16 + ((cb + 4 + q) ^ swz)) * 8];
        __builtin_amdgcn_s_setprio(1);
        acc0 = __builtin_amdgcn_mfma_f32_16x16x32_bf16(a00, b0, acc0, 0, 0, 0);
        acc1 = __builtin_amdgcn_mfma_f32_16x16x32_bf16(a10, b0, acc1, 0, 0, 0);
        acc0 = __builtin_amdgcn_mfma_f32_16x16x32_bf16(a01, b1, acc0, 0, 0, 0);
        acc1 = __builtin_amdgcn_mfma_f32_16x16x32_bf16(a11, b1, acc1, 0, 0, 0);
        __builtin_amdgcn_s_setprio(0);
    }
#undef STAGE

    // ---- cross-wk reduction via LDS (conflict-free: stride-1 lanes) ----
    __syncthreads();
    float* red = (float*)&lds[0][0][0];   // 8 * 128 floats = 4 KB
    if (wk == 1) {
        #pragma unroll
        for (int r = 0; r < 4; ++r) {
            red[r * 128 + wn * 64 + lane]       = acc0[r];
            red[(r + 4) * 128 + wn * 64 + lane] = acc1[r];
        }
    }
    __syncthreads();
    if (wk != 0) return;
    #pragma unroll
    for (int r = 0; r < 4; ++r) {
        acc0[r] += red[r * 128 + wn * 64 + lane];
        acc1[r] += red[(r + 4) * 128 + wn * 64 + lane];
    }

    // epilogue: lane holds D[row = 16*mA + 4*q + r][col = 16*wn + c16]
    const int gcol = n0 + 16 * wn + c16;
    const float b0s = bias[gcol];
    #pragma unroll
    for (int mA = 0; mA < 2; ++mA) {
        v4f acc = mA ? acc1 : acc0;
        #pragma unroll
        for (int r = 0; r < 4; ++r) {
            const int grow = m0 + 16 * mA + 4 * q + r;
            const float v = acc[r] + b0s;
            const long idx = (long)grow * N + gcol;
            if (mode == 0) {
                obf[idx] = (__bf16)fast_tanh(v);
            } else if (mode == 1) {
                S[idx] = v;
                obf[idx] = (__bf16)(y[idx] + cc * v);
            } else if (mode == 2) {
                S[idx] += 2.0f * v;
                obf[idx] = (__bf16)(y[idx] + cc * v);
            } else {
                float yn = y[idx] + dt6 * (S[idx] + v);
                y[idx] = yn;
                obf[idx] = (__bf16)yn;
                traj[idx] = yn;
            }
        }
    }
}

// ---------- host ----------
extern "C" void kernel_launch(void* const* d_in, const int* in_sizes, int n_in,
                              void* d_out, int out_size, void* d_ws, size_t ws_size,
                              hipStream_t stream) {
    const float* z     = (const float*)d_in[0];
    const float* decW  = (const float*)d_in[1];
    const float* decb  = (const float*)d_in[2];
    const float* tmpl  = (const float*)d_in[3];
    const float* dW1   = (const float*)d_in[4];
    const float* db1   = (const float*)d_in[5];
    const float* dW2   = (const float*)d_in[6];
    const float* db2   = (const float*)d_in[7];
    const float* aW1   = (const float*)d_in[8];
    const float* ab1   = (const float*)d_in[9];
    const float* aW2   = (const float*)d_in[10];
    const float* ab2   = (const float*)d_in[11];
    const float* odeW1 = (const float*)d_in[12];
    const float* odeb1 = (const float*)d_in[13];
    const float* odeW2 = (const float*)d_in[14];
    const float* odeb2 = (const float*)d_in[15];
    float* out = (float*)d_out;

    char* ws = (char*)d_ws;
    size_t off = 0;
    auto alloc = [&](size_t bytes) -> void* {
        void* p = ws + off;
        off = (off + bytes + 255) & ~(size_t)255;
        return p;
    };
    __bf16* w1t = (__bf16*)alloc((size_t)4096 * 3200 * 2);  // W1^T: (4096 x 3200)
    __bf16* w2t = (__bf16*)alloc((size_t)3200 * 4096 * 2);  // W2^T: (3200 x 4096)
    float*  SE  = (float*)alloc((size_t)128 * 2048 * 4);
    float*  yst = (float*)alloc((size_t)409600 * 4);
    float*  Sac = (float*)alloc((size_t)409600 * 4);
    __bf16* ybf = (__bf16*)alloc((size_t)409600 * 2);
    __bf16* hbf = (__bf16*)alloc((size_t)128 * 4096 * 2);

    // weights -> bf16 transposed
    transpose_bf16<<<dim3(128, 100), 256, 0, stream>>>(odeW1, w1t, 3200, 4096);
    transpose_bf16<<<dim3(100, 128), 256, 0, stream>>>(odeW2, w2t, 4096, 3200);
    // y0 setup
    se_kernel<<<128, 256, 0, stream>>>(z, decW, decb, SE);
    init_kernel<<<4096, 128, 0, stream>>>(SE, tmpl, dW1, db1, dW2, db2,
                                          aW1, ab1, aW2, ab2, yst, ybf, out);

    const float dt  = 8.0f / 191.0f;
    const float dt2 = 0.5f * dt;
    const float dt6 = dt / 6.0f;

    // GEMM1: N=4096 -> nTiles=128, grid = (128/8)*32 = 512 (2 blocks/CU)
    // GEMM2: N=3200 -> nTiles=100, grid = ceil(100/8)*32 = 416 (16 blocks early-exit)
    for (int s = 0; s < 191; ++s) {
        float* traj = out + (size_t)(s + 1) * 409600;
        // eval 1
        gemm_step<<<512, 256, 0, stream>>>(ybf, w1t, odeb1, 3200, 128, 0, 0.f, 0.f,
                                           hbf, nullptr, nullptr, nullptr);
        gemm_step<<<416, 256, 0, stream>>>(hbf, w2t, odeb2, 4096, 100, 1, dt2, dt6,
                                           ybf, yst, Sac, nullptr);
        // eval 2
        gemm_step<<<512, 256, 0, stream>>>(ybf, w1t, odeb1, 3200, 128, 0, 0.f, 0.f,
                                           hbf, nullptr, nullptr, nullptr);
        gemm_step<<<416, 256, 0, stream>>>(hbf, w2t, odeb2, 4096, 100, 2, dt2, dt6,
                                           ybf, yst, Sac, nullptr);
        // eval 3
        gemm_step<<<512, 256, 0, stream>>>(ybf, w1t, odeb1, 3200, 128, 0, 0.f, 0.f,
                                           hbf, nullptr, nullptr, nullptr);
        gemm_step<<<416, 256, 0, stream>>>(hbf, w2t, odeb2, 4096, 100, 2, dt, dt6,
                                           ybf, yst, Sac, nullptr);
        // eval 4 + RK4 combine + trajectory write
        gemm_step<<<512, 256, 0, stream>>>(ybf, w1t, odeb1, 3200, 128, 0, 0.f, 0.f,
                                           hbf, nullptr, nullptr, nullptr);
        gemm_step<<<416, 256, 0, stream>>>(hbf, w2t, odeb2, 4096, 100, 3, 0.f, dt6,
                                           ybf, yst, Sac, traj);
    }
}

// Round 2
// 21557.639 us; speedup vs baseline: 1.0661x; 1.0661x over previous
//
#include <hip/hip_runtime.h>
#include <hip/hip_bf16.h>

// ---------- types ----------
typedef __bf16 v8bf __attribute__((ext_vector_type(8)));
typedef float  v4f  __attribute__((ext_vector_type(4)));
typedef float  v16f __attribute__((ext_vector_type(16)));

__device__ inline const __attribute__((address_space(1))) void* gcast(const void* p) {
    return (const __attribute__((address_space(1))) void*)p;
}
__device__ inline __attribute__((address_space(3))) void* scast(void* p) {
    return (__attribute__((address_space(3))) void*)p;
}

__device__ inline float fast_tanh(float x) {
    float e = __expf(2.0f * x);
    return 1.0f - 2.0f / (e + 1.0f);
}

// ---------- setup kernel 1: SE = z @ dec_W + dec_b  (128 x 2048) ----------
__global__ __launch_bounds__(256) void se_kernel(const float* __restrict__ z,
                                                 const float* __restrict__ decW,
                                                 const float* __restrict__ decb,
                                                 float* __restrict__ SE) {
    __shared__ float zs[128];
    const int b = blockIdx.x, t = threadIdx.x;
    if (t < 128) zs[t] = z[b * 128 + t];
    __syncthreads();
    for (int c = t; c < 2048; c += 256) {
        float acc = decb[c];
        #pragma unroll 4
        for (int k = 0; k < 128; ++k) acc += zs[k] * decW[k * 2048 + c];
        SE[b * 2048 + c] = acc;
    }
}

// ---------- setup kernel 2: deformation + aliveness + y0 assembly ----------
__global__ __launch_bounds__(128) void init_kernel(
    const float* __restrict__ SE, const float* __restrict__ tmpl,
    const float* __restrict__ dW1, const float* __restrict__ db1,
    const float* __restrict__ dW2, const float* __restrict__ db2,
    const float* __restrict__ aW1, const float* __restrict__ ab1,
    const float* __restrict__ aW2, const float* __restrict__ ab2,
    float* __restrict__ y, __bf16* __restrict__ ybf, float* __restrict__ out0) {
    __shared__ float se[64];
    __shared__ float h[128];
    __shared__ float ah[32];
    __shared__ float alive;
    const int r = blockIdx.x, b = r >> 5, s = r & 31, t = threadIdx.x;
    if (t < 64) se[t] = SE[b * 2048 + s * 64 + t];
    __syncthreads();
    {
        float acc = db1[t];
        #pragma unroll 4
        for (int k = 0; k < 64; ++k) acc += se[k] * dW1[k * 128 + t];
        h[t] = fmaxf(acc, 0.0f);
    }
    if (t < 32) {
        float acc = ab1[t];
        #pragma unroll 4
        for (int k = 0; k < 64; ++k) acc += se[k] * aW1[k * 32 + t];
        ah[t] = fmaxf(acc, 0.0f);
    }
    __syncthreads();
    if (t == 0) {
        float lg = ab2[0];
        #pragma unroll
        for (int j = 0; j < 32; ++j) lg += ah[j] * aW2[j];
        alive = 1.0f / (1.0f + __expf(-lg));
    }
    __syncthreads();
    if (t < 99) {
        float acc = db2[t];
        #pragma unroll 4
        for (int j = 0; j < 128; ++j) acc += h[j] * dW2[j * 99 + t];
        float v = (tmpl[s * 99 + t] + acc) * alive;
        int idx = b * 3200 + s * 99 + t;
        y[idx] = v; ybf[idx] = (__bf16)v; out0[idx] = v;
    } else if (t == 99) {
        int idx = b * 3200 + 3168 + s;
        y[idx] = alive; ybf[idx] = (__bf16)alive; out0[idx] = alive;
    }
}

// ---------- transpose fp32 (R x C) -> bf16 (C x R) ----------
__global__ __launch_bounds__(256) void transpose_bf16(const float* __restrict__ W,
                                                      __bf16* __restrict__ WT,
                                                      int R, int C) {
    __shared__ float tile[32][33];
    const int tx = threadIdx.x & 31, ty = threadIdx.x >> 5;
    const int c0 = blockIdx.x * 32, r0 = blockIdx.y * 32;
    #pragma unroll
    for (int i = 0; i < 4; ++i)
        tile[ty + 8 * i][tx] = W[(long)(r0 + ty + 8 * i) * C + c0 + tx];
    __syncthreads();
    #pragma unroll
    for (int i = 0; i < 4; ++i)
        WT[(long)(c0 + ty + 8 * i) * R + r0 + tx] = (__bf16)tile[tx][ty + 8 * i];
}

// ---------- main GEMM: C(128 x N) = A(128 x K, bf16) * BT(N x K, bf16)^T ----------
// BM=32, BN=32, BK=128, 256 threads = 4 waves, wave w = K-quarter wk (K-split-4).
// Each wave computes the FULL 32x32 tile over its K-quarter with
// v_mfma_f32_32x32x16_bf16 (2 MFMA/iter) -> zero LDS read redundancy
// (16 KB staged + 16 KB read per block-iter vs 16+24 with the 16x16 shape),
// half the MFMA/ds_read instruction count for the same FLOP.
// 4-deep LDS pipeline (64 KB), counted vmcnt (8/4/0 — never drains in steady
// state), one raw s_barrier per K-iter. Cross-wk reduction via LDS at the end;
// epilogue split across all 4 waves (wave w owns output rows 8w..8w+7 per the
// measured 32x32 C/D mapping: row=(reg&3)+8*(reg>>2)+4*(lane>>5), col=lane&31).
// Grid is XCD-grouped: the 4 mt-blocks sharing one B-strip get bids = same
// (mod 8) so they land on one XCD's L2. grid = ceil(nTiles/8)*32; blocks with
// nt >= nTiles early-exit.
// mode 0: H = tanh(C + bias) -> obf (bf16)                       [phase 1]
// mode 1: k=C+bias; S=k;      ybf=bf16(y + cc*k)                 [eval 1]
// mode 2: k=C+bias; S+=2k;    ybf=bf16(y + cc*k)                 [evals 2,3]
// mode 3: k=C+bias; yn=y+dt6*(S+k); y=yn; ybf=bf16(yn); traj=yn  [eval 4]
__global__ __launch_bounds__(256, 2) void gemm_step(
    const __bf16* __restrict__ A, const __bf16* __restrict__ BT,
    const float* __restrict__ bias, int K, int nTiles, int mode, float cc, float dt6,
    __bf16* __restrict__ obf, float* __restrict__ y, float* __restrict__ S,
    float* __restrict__ traj) {
    // lds[buf][0] = A tile 32x128, lds[buf][1] = B tile 32x128 (each 8 KB).
    // XOR-swizzled chunk layout: chunk(row, c) stored at slot row*16 + (c ^ (row&15));
    // staging is contiguous 16B/lane (global_load_lds-compatible), reads spread
    // across all bank quads (minimum aliasing).
    __shared__ __attribute__((aligned(16))) __bf16 lds[4][2][4096];

    const int t = threadIdx.x;
    const int lane = t & 63, w = t >> 6;          // w = wk (K-quarter index)

    const int g = blockIdx.x >> 5, rr = blockIdx.x & 31;
    const int nt = g * 8 + (rr & 7);
    const int mt = rr >> 3;
    if (nt >= nTiles) return;
    const int m0 = mt * 32, n0 = nt * 32;
    const int N = nTiles * 32;

    // staging: thread t stages 4 chunks/iter (2 A rows, 2 B rows, same chunk slot)
    const int sr = t >> 4;               // 0..15
    const int scg = (t & 15) ^ sr;       // global chunk for stored slot (t&15)
    const __bf16* pA0 = A  + (long)(m0 + sr)      * K + scg * 8;
    const __bf16* pA1 = A  + (long)(m0 + sr + 16) * K + scg * 8;  // (sr+16)&15 == sr
    const __bf16* pB0 = BT + (long)(n0 + sr)      * K + scg * 8;
    const __bf16* pB1 = BT + (long)(n0 + sr + 16) * K + scg * 8;

    v16f acc = {0.f, 0.f, 0.f, 0.f, 0.f, 0.f, 0.f, 0.f,
                0.f, 0.f, 0.f, 0.f, 0.f, 0.f, 0.f, 0.f};

    // read offsets: A-frag lane l -> A[row=l&31][k = wk*32 + i*16 + (l>>5)*8 + j]
    //               B-frag lane l -> BT[col=l&31][same k]   (identical chunk math)
    const int frow = lane & 31;                 // 0..31 (row of A / row of BT = col)
    const int sw   = lane & 15;                 // swizzle key (row & 15)
    const int cc0  = w * 4 + (lane >> 5);       // chunk of MFMA i=0
    const int cc1  = cc0 + 2;                   // chunk of MFMA i=1
    const int off0 = (frow * 16 + (cc0 ^ sw)) * 8;   // elem offset into 4096
    const int off1 = (frow * 16 + (cc1 ^ sw)) * 8;

    const int nIter = K >> 7;

#define STAGE(buf, koff) do { \
    __builtin_amdgcn_global_load_lds(gcast(pA0 + (koff)), scast(&lds[buf][0][t * 8]),         16, 0, 0); \
    __builtin_amdgcn_global_load_lds(gcast(pA1 + (koff)), scast(&lds[buf][0][(t + 256) * 8]), 16, 0, 0); \
    __builtin_amdgcn_global_load_lds(gcast(pB0 + (koff)), scast(&lds[buf][1][t * 8]),         16, 0, 0); \
    __builtin_amdgcn_global_load_lds(gcast(pB1 + (koff)), scast(&lds[buf][1][(t + 256) * 8]), 16, 0, 0); \
} while (0)

    // prologue: prefetch 3 tiles ahead
    STAGE(0, 0);
    if (nIter > 1) STAGE(1, 128);
    if (nIter > 2) STAGE(2, 256);

    for (int it = 0; it < nIter; ++it) {
        const int ahead = nIter - 1 - it;
        __builtin_amdgcn_sched_barrier(0);
        if (ahead >= 2)      asm volatile("s_waitcnt vmcnt(8)" ::: "memory");
        else if (ahead == 1) asm volatile("s_waitcnt vmcnt(4)" ::: "memory");
        else                 asm volatile("s_waitcnt vmcnt(0)" ::: "memory");
        __builtin_amdgcn_sched_barrier(0);
        __builtin_amdgcn_s_barrier();       // cur filled; everyone done with it-1
        __builtin_amdgcn_sched_barrier(0);
        // refill the buffer freed at iter it-1 ((it+3)&3 == (it-1)&3)
        if (it + 3 < nIter) STAGE((it + 3) & 3, (it + 3) * 128);

        const __bf16* bufA = lds[it & 3][0];
        const __bf16* bufB = lds[it & 3][1];
        v8bf a0 = *(const v8bf*)&bufA[off0];
        v8bf b0 = *(const v8bf*)&bufB[off0];
        v8bf a1 = *(const v8bf*)&bufA[off1];
        v8bf b1 = *(const v8bf*)&bufB[off1];
        __builtin_amdgcn_s_setprio(1);
        acc = __builtin_amdgcn_mfma_f32_32x32x16_bf16(a0, b0, acc, 0, 0, 0);
        acc = __builtin_amdgcn_mfma_f32_32x32x16_bf16(a1, b1, acc, 0, 0, 0);
        __builtin_amdgcn_s_setprio(0);
    }
#undef STAGE

    // ---- cross-wk reduction via LDS (lane-contiguous v4f, conflict-free) ----
    // red[w'][q][lane][c]: wave w' writes its 4 reg-quads; wave w sums quad w.
    __syncthreads();
    float* red = (float*)&lds[0][0][0];   // 4*4*64*4 floats = 16 KB
    #pragma unroll
    for (int qq = 0; qq < 4; ++qq) {
        v4f part = {acc[4 * qq + 0], acc[4 * qq + 1], acc[4 * qq + 2], acc[4 * qq + 3]};
        *(v4f*)&red[((w * 4 + qq) * 64 + lane) * 4] = part;
    }
    __syncthreads();
    v4f sum = {0.f, 0.f, 0.f, 0.f};
    #pragma unroll
    for (int ww = 0; ww < 4; ++ww) {
        v4f p = *(const v4f*)&red[((ww * 4 + w) * 64 + lane) * 4];
        sum += p;
    }

    // epilogue: regs r = 4w+c -> row = c + 8w + 4*(lane>>5), col = lane&31
    const int gcol = n0 + (lane & 31);
    const float bs = bias[gcol];
    const int rbase = m0 + 8 * w + 4 * (lane >> 5);
    #pragma unroll
    for (int c = 0; c < 4; ++c) {
        const int grow = rbase + c;
        const float v = sum[c] + bs;
        const long idx = (long)grow * N + gcol;
        if (mode == 0) {
            obf[idx] = (__bf16)fast_tanh(v);
        } else if (mode == 1) {
            S[idx] = v;
            obf[idx] = (__bf16)(y[idx] + cc * v);
        } else if (mode == 2) {
            S[idx] += 2.0f * v;
            obf[idx] = (__bf16)(y[idx] + cc * v);
        } else {
            float yn = y[idx] + dt6 * (S[idx] + v);
            y[idx] = yn;
            obf[idx] = (__bf16)yn;
            traj[idx] = yn;
        }
    }
}

// ---------- host ----------
extern "C" void kernel_launch(void* const* d_in, const int* in_sizes, int n_in,
                              void* d_out, int out_size, void* d_ws, size_t ws_size,
                              hipStream_t stream) {
    const float* z     = (const float*)d_in[0];
    const float* decW  = (const float*)d_in[1];
    const float* decb  = (const float*)d_in[2];
    const float* tmpl  = (const float*)d_in[3];
    const float* dW1   = (const float*)d_in[4];
    const float* db1   = (const float*)d_in[5];
    const float* dW2   = (const float*)d_in[6];
    const float* db2   = (const float*)d_in[7];
    const float* aW1   = (const float*)d_in[8];
    const float* ab1   = (const float*)d_in[9];
    const float* aW2   = (const float*)d_in[10];
    const float* ab2   = (const float*)d_in[11];
    const float* odeW1 = (const float*)d_in[12];
    const float* odeb1 = (const float*)d_in[13];
    const float* odeW2 = (const float*)d_in[14];
    const float* odeb2 = (const float*)d_in[15];
    float* out = (float*)d_out;

    char* ws = (char*)d_ws;
    size_t off = 0;
    auto alloc = [&](size_t bytes) -> void* {
        void* p = ws + off;
        off = (off + bytes + 255) & ~(size_t)255;
        return p;
    };
    __bf16* w1t = (__bf16*)alloc((size_t)4096 * 3200 * 2);  // W1^T: (4096 x 3200)
    __bf16* w2t = (__bf16*)alloc((size_t)3200 * 4096 * 2);  // W2^T: (3200 x 4096)
    float*  SE  = (float*)alloc((size_t)128 * 2048 * 4);
    float*  yst = (float*)alloc((size_t)409600 * 4);
    float*  Sac = (float*)alloc((size_t)409600 * 4);
    __bf16* ybf = (__bf16*)alloc((size_t)409600 * 2);
    __bf16* hbf = (__bf16*)alloc((size_t)128 * 4096 * 2);

    // weights -> bf16 transposed
    transpose_bf16<<<dim3(128, 100), 256, 0, stream>>>(odeW1, w1t, 3200, 4096);
    transpose_bf16<<<dim3(100, 128), 256, 0, stream>>>(odeW2, w2t, 4096, 3200);
    // y0 setup
    se_kernel<<<128, 256, 0, stream>>>(z, decW, decb, SE);
    init_kernel<<<4096, 128, 0, stream>>>(SE, tmpl, dW1, db1, dW2, db2,
                                          aW1, ab1, aW2, ab2, yst, ybf, out);

    const float dt  = 8.0f / 191.0f;
    const float dt2 = 0.5f * dt;
    const float dt6 = dt / 6.0f;

    // GEMM1: N=4096 -> nTiles=128, grid = (128/8)*32 = 512 (2 blocks/CU)
    // GEMM2: N=3200 -> nTiles=100, grid = ceil(100/8)*32 = 416 (16 blocks early-exit)
    for (int s = 0; s < 191; ++s) {
        float* traj = out + (size_t)(s + 1) * 409600;
        // eval 1
        gemm_step<<<512, 256, 0, stream>>>(ybf, w1t, odeb1, 3200, 128, 0, 0.f, 0.f,
                                           hbf, nullptr, nullptr, nullptr);
        gemm_step<<<416, 256, 0, stream>>>(hbf, w2t, odeb2, 4096, 100, 1, dt2, dt6,
                                           ybf, yst, Sac, nullptr);
        // eval 2
        gemm_step<<<512, 256, 0, stream>>>(ybf, w1t, odeb1, 3200, 128, 0, 0.f, 0.f,
                                           hbf, nullptr, nullptr, nullptr);
        gemm_step<<<416, 256, 0, stream>>>(hbf, w2t, odeb2, 4096, 100, 2, dt2, dt6,
                                           ybf, yst, Sac, nullptr);
        // eval 3
        gemm_step<<<512, 256, 0, stream>>>(ybf, w1t, odeb1, 3200, 128, 0, 0.f, 0.f,
                                           hbf, nullptr, nullptr, nullptr);
        gemm_step<<<416, 256, 0, stream>>>(hbf, w2t, odeb2, 4096, 100, 2, dt, dt6,
                                           ybf, yst, Sac, nullptr);
        // eval 4 + RK4 combine + trajectory write
        gemm_step<<<512, 256, 0, stream>>>(ybf, w1t, odeb1, 3200, 128, 0, 0.f, 0.f,
                                           hbf, nullptr, nullptr, nullptr);
        gemm_step<<<416, 256, 0, stream>>>(hbf, w2t, odeb2, 4096, 100, 3, 0.f, dt6,
                                           ybf, yst, Sac, traj);
    }
}